// Round 7
// baseline (527.558 us; speedup 1.0000x reference)
//
#include <hip/hip_runtime.h>
#include <math.h>

#define BUCKET_SHIFT 7                 // 128 nodes per bucket
#define BUCKET_NODES (1 << BUCKET_SHIFT)
#define MAX_BUCK 512                   // >= ceil(N / BUCKET_NODES)
#define PART_CHUNK 8192
#define PART_EPT 32                    // PART_CHUNK / 256

typedef _Float16 half4v __attribute__((ext_vector_type(4)));
typedef _Float16 half8v __attribute__((ext_vector_type(8)));

__device__ __forceinline__ float leaky02(float x){ return x > 0.f ? x : 0.2f * x; }
__device__ __forceinline__ float eluf(float x){ return x > 0.f ? x : expm1f(x); }

// ---------------- launch 1: gemm1 (16 rows/block, 256 thr) + bucket-hist blocks -----
// Blocks [0, histBlocks): per-chunk LDS histogram of dst buckets -> bucketPartial[b][j]
// (no global atomics, no pre-zero needed). Block 0 also zeroes pooled/cntG.
// Blocks [histBlocks, ...): h1 = x @ W1 fp16 out + fused alpha dots.
__global__ __launch_bounds__(256) void gemm1_hist_kernel(
    const float* __restrict__ x, const float* __restrict__ W,
    const float* __restrict__ a_src, const float* __restrict__ a_dst, // flat [128]
    _Float16* __restrict__ h, float* __restrict__ as_, float* __restrict__ ad_, int n,
    const int* __restrict__ dstv, int* __restrict__ bucketPartial, int pbPad,
    int E, int K, int histBlocks,
    int* __restrict__ zbase, int zwords)
{
  const int t = threadIdx.x;
  if (blockIdx.x < histBlocks) {
    // ---- histogram part ----
    __shared__ int hist[MAX_BUCK];
    for (int b = t; b < K; b += 256) hist[b] = 0;
    __syncthreads();
    const int j = blockIdx.x;
    int cbase = j * PART_CHUNK;
    for (int q = 0; q < PART_EPT; ++q) {
      int e = cbase + q * 256 + t;
      if (e < E) atomicAdd(&hist[dstv[e] >> BUCKET_SHIFT], 1);
    }
    __syncthreads();
    for (int b = t; b < K; b += 256)
      bucketPartial[(size_t)b * pbPad + j] = hist[b];
    if (j == 0) {
      for (int i = t; i < zwords; i += 256) zbase[i] = 0;
    }
    return;
  }
  // ---- gemm part ----
  const int g = blockIdx.x - histBlocks;
  const int row0 = g * 16;
  __shared__ float xs[16][128];
  __shared__ float sS[16][128];
  __shared__ float sD[16][128];
  for (int idx = t; idx < 16 * 32; idx += 256) {
    int r = idx >> 5, k4 = idx & 31;
    float4 v = (row0 + r < n) ? ((const float4*)x)[(size_t)(row0 + r) * 32 + k4]
                              : make_float4(0.f, 0.f, 0.f, 0.f);
    *(float4*)&xs[r][k4 * 4] = v;
  }
  __syncthreads();
  const int col = t & 127, hf = t >> 7;
  float acc[8] = {0,0,0,0,0,0,0,0};
  for (int k = 0; k < 128; k += 4) {
    float w0 = W[(k + 0) * 128 + col];
    float w1 = W[(k + 1) * 128 + col];
    float w2 = W[(k + 2) * 128 + col];
    float w3 = W[(k + 3) * 128 + col];
    #pragma unroll
    for (int r = 0; r < 8; ++r) {
      const float4 xv = *(const float4*)&xs[hf * 8 + r][k];
      acc[r] += xv.x * w0 + xv.y * w1 + xv.z * w2 + xv.w * w3;
    }
  }
  float asv = a_src[col], adv = a_dst[col];
  #pragma unroll
  for (int r = 0; r < 8; ++r) {
    int row = hf * 8 + r;
    float hv = acc[r];
    if (row0 + row < n) h[(size_t)(row0 + row) * 128 + col] = (_Float16)hv;
    sS[row][col] = hv * asv;
    sD[row][col] = hv * adv;
  }
  __syncthreads();
  if (t < 128) {
    int r = t >> 3, head = (t >> 1) & 3, which = t & 1;
    if (row0 + r < n) {
      const float (*buf)[128] = which ? sD : sS;
      double s2 = 0;
      for (int cc = 0; cc < 32; ++cc) s2 += (double)buf[r][head * 32 + cc];
      (which ? ad_ : as_)[(row0 + r) * 4 + head] = (float)s2;
    }
  }
}

// ---------------- launch 2: 2-D scan — per-(bucket,block) exclusive offsets ---------
// Column scan over j per bucket (contiguous row reads), then exclusive scan over b.
__global__ __launch_bounds__(256) void scan2d_kernel(
    int* __restrict__ partial, int pbPad, int* __restrict__ bucketStart, int pb, int K)
{
  int t = threadIdx.x;
  for (int b = t; b < K; b += 256) {
    int run = 0;
    int* row = partial + (size_t)b * pbPad;
    for (int j = 0; j < pb; ++j) { int v = row[j]; row[j] = run; run += v; }
    bucketStart[b] = run;
  }
  __syncthreads();
  __shared__ int s[256];
  __shared__ int carry_s;
  if (t == 0) carry_s = 0;
  __syncthreads();
  for (int base = 0; base < K; base += 256) {
    int v = (base + t < K) ? bucketStart[base + t] : 0;
    s[t] = v;
    __syncthreads();
    for (int off = 1; off < 256; off <<= 1) {
      int xv = (t >= off) ? s[t - off] : 0;
      __syncthreads();
      s[t] += xv;
      __syncthreads();
    }
    int incl = s[t];
    int carry = carry_s;
    if (base + t < K) bucketStart[base + t] = carry + incl - v;   // exclusive
    __syncthreads();
    if (t == 255) carry_s = carry + incl;
    __syncthreads();
  }
}

// ---------------- launch 3: partition — pure scatter, no global atomics -------------
// base per (block,bucket) comes from scan2d; packed record (src<<7)|(dst&127).
__global__ __launch_bounds__(256) void partition_kernel(
    const int* __restrict__ src, const int* __restrict__ dst,
    const int* __restrict__ bucketStart, const int* __restrict__ pre, int pbPad,
    unsigned int* __restrict__ bucketed, int E, int K)
{
  __shared__ int base_s[MAX_BUCK];
  __shared__ int cur[MAX_BUCK];
  const int j = blockIdx.x;
  for (int b = threadIdx.x; b < K; b += 256) {
    base_s[b] = bucketStart[b] + pre[(size_t)b * pbPad + j];
    cur[b] = 0;
  }
  __syncthreads();
  int cbase = j * PART_CHUNK;
  for (int q = 0; q < PART_EPT; ++q) {
    int e = cbase + q * 256 + threadIdx.x;
    if (e < E) {
      int d = dst[e];
      int b = d >> BUCKET_SHIFT;
      int r = atomicAdd(&cur[b], 1);
      bucketed[base_s[b] + r] =
          ((unsigned int)src[e] << BUCKET_SHIFT) | (unsigned int)(d & (BUCKET_NODES - 1));
    }
  }
}

// ---------------- launch 4: per-bucket LDS hist -> scan -> rowStart -> fine fill ----
__global__ __launch_bounds__(256) void fill_csr_kernel(
    const unsigned int* __restrict__ bucketed, const int* __restrict__ bucketStart,
    int* __restrict__ rowStart, int* __restrict__ col, int n, int E, int K)
{
  int b = blockIdx.x;
  int nodeBase = b << BUCKET_SHIFT;
  int t = threadIdx.x;
  __shared__ int hist[BUCKET_NODES];
  __shared__ int rs[BUCKET_NODES];
  __shared__ int cur[BUCKET_NODES];
  if (t < BUCKET_NODES) hist[t] = 0;
  __syncthreads();
  int bs = bucketStart[b];
  int be = (b + 1 < K) ? bucketStart[b + 1] : E;
  for (int i = bs + t; i < be; i += 256)
    atomicAdd(&hist[bucketed[i] & (BUCKET_NODES - 1)], 1);
  __syncthreads();
  if (t < BUCKET_NODES) rs[t] = hist[t];
  __syncthreads();
  for (int off = 1; off < BUCKET_NODES; off <<= 1) {
    int v = (t < BUCKET_NODES && t >= off) ? rs[t - off] : 0;
    __syncthreads();
    if (t < BUCKET_NODES) rs[t] += v;
    __syncthreads();
  }
  if (t < BUCKET_NODES) {
    int node = nodeBase + t;
    int excl = bs + rs[t] - hist[t];      // exclusive start, absolute
    if (node < n) rowStart[node] = excl;
    rs[t] = excl;
    cur[t] = 0;
  }
  if (b == K - 1 && t == 0) rowStart[n] = E;
  __syncthreads();
  for (int i = bs + t; i < be; i += 256) {
    unsigned int rec = bucketed[i];
    int local = rec & (BUCKET_NODES - 1);
    int pos = rs[local] + atomicAdd(&cur[local], 1);
    col[pos] = (int)(rec >> BUCKET_SHIFT);
  }
}

// ---------------- launch 5: GAT aggregation layer 1 (f32 accumulators) --------------
__global__ __launch_bounds__(256) void gat_aggr1_kernel(
    const _Float16* __restrict__ feat,  // [n][128] fp16
    const float* __restrict__ as_,      // [n][4]
    const float* __restrict__ ad_,      // [n][4]
    const int* __restrict__ rowStart,
    const int* __restrict__ col,
    const float* __restrict__ bias,     // [128]
    _Float16* __restrict__ out, int n)  // [n][128] fp16
{
  constexpr int CHUNK = 16;
  const int t    = threadIdx.x;
  const int wave = t >> 6;
  const int lane = t & 63;
  const int grp  = lane >> 4;
  const int li   = lane & 15;
  const int slot = wave * 4 + grp;
  const int node = blockIdx.x * 16 + slot;
  const int hc   = li >> 2;

  __shared__ int   s_off[16][CHUNK];
  __shared__ float s_p[16][CHUNK * 4];

  if (node >= n) return;   // safe: wave-private, no block barriers

  const int beg = rowStart[node];
  const int deg = rowStart[node + 1] - beg;

  const float4 advv = ((const float4*)ad_)[node];
  const float4 asvv = ((const float4*)as_)[node];
  const float adv[4] = {advv.x, advv.y, advv.z, advv.w};
  float es;
  {
    float e0 = leaky02(asvv.x + adv[0]);
    float e1 = leaky02(asvv.y + adv[1]);
    float e2 = leaky02(asvv.z + adv[2]);
    float e3 = leaky02(asvv.w + adv[3]);
    es = (hc == 0) ? e0 : (hc == 1) ? e1 : (hc == 2) ? e2 : e3;
  }
  const float ps = expf(es);

  const char* featc = (const char*)feat + (li << 4);   // +16 B per lane, 256 B rows
  const half8v fself = *(const half8v*)(featc + ((size_t)node << 8));
  float accf[8];
  #pragma unroll
  for (int q = 0; q < 8; ++q) accf[q] = ps * (float)fself[q];
  float den = ps;

  // staging registers (1 edge per lane)
  int    st_s = 0;
  float4 st_q = make_float4(0.f, 0.f, 0.f, 0.f);
  if (deg > 0 && li < min(CHUNK, deg)) {
    st_s = col[beg + li];
    st_q = ((const float4*)as_)[st_s];
  }

  const int nch = (deg + CHUNK - 1) / CHUNK;
  for (int c = 0; c < nch; ++c) {
    const int base = c * CHUNK;
    const int cnt  = min(CHUNK, deg - base);
    if (li < cnt) {
      s_off[slot][li] = st_s << 8;
      float4 pp;
      pp.x = expf(leaky02(st_q.x + adv[0]));
      pp.y = expf(leaky02(st_q.y + adv[1]));
      pp.z = expf(leaky02(st_q.z + adv[2]));
      pp.w = expf(leaky02(st_q.w + adv[3]));
      *(float4*)&s_p[slot][li * 4] = pp;
    }
    __builtin_amdgcn_wave_barrier();   // staging before consumption
    const int nbase = base + CHUNK;
    if (nbase + li < deg) {
      st_s = col[beg + nbase + li];
      st_q = ((const float4*)as_)[st_s];
    }
    float a[8] = {0,0,0,0,0,0,0,0};
    float df = 0.f;
    if (cnt == CHUNK) {
      int off[16];
      #pragma unroll
      for (int j = 0; j < 16; ++j) off[j] = s_off[slot][j];
      half8v r[16];
      #pragma unroll
      for (int j = 0; j < 16; ++j) r[j] = *(const half8v*)(featc + off[j]);
      #pragma unroll
      for (int j = 0; j < 16; ++j) {
        float p = s_p[slot][j * 4 + hc];
        #pragma unroll
        for (int q = 0; q < 8; ++q) a[q] += p * (float)r[j][q];
        df += p;
      }
    } else {
      for (int j = 0; j < cnt; ++j) {
        int off = s_off[slot][j];
        float p = s_p[slot][j * 4 + hc];
        const half8v f = *(const half8v*)(featc + off);
        #pragma unroll
        for (int q = 0; q < 8; ++q) a[q] += p * (float)f[q];
        df += p;
      }
    }
    __builtin_amdgcn_wave_barrier();   // consumption before next staging
    #pragma unroll
    for (int q = 0; q < 8; ++q) accf[q] += a[q];
    den += df;
  }

  const float4 bv0 = ((const float4*)bias)[2 * li];
  const float4 bv1 = ((const float4*)bias)[2 * li + 1];
  const float bb[8] = {bv0.x, bv0.y, bv0.z, bv0.w, bv1.x, bv1.y, bv1.z, bv1.w};
  const float inv = 1.0f / den;
  half8v ov;
  #pragma unroll
  for (int q = 0; q < 8; ++q)
    ov[q] = (_Float16)eluf(accf[q] * inv + bb[q]);
  *(half8v*)((char*)out + ((size_t)node << 8) + (li << 4)) = ov;
}

// ---------------- launch 6: GEMM2 (N x 128 fp16) @ (128 x 32), fused alphas ---------
__global__ __launch_bounds__(128) void gemm2_kernel(
    const _Float16* __restrict__ x, const float* __restrict__ W,
    const float* __restrict__ a_src, const float* __restrict__ a_dst, // [32]
    _Float16* __restrict__ h, float* __restrict__ as_, float* __restrict__ ad_, int n)
{
  const int t = threadIdx.x;
  const int row0 = blockIdx.x * 8;
  __shared__ float xs[8][128];
  __shared__ float sH[8][32];
  for (int idx = t; idx < 8 * 16; idx += 128) {
    int r = idx >> 4, k8 = idx & 15;
    half8v v;
    #pragma unroll
    for (int q = 0; q < 8; ++q) v[q] = (_Float16)0.f;
    if (row0 + r < n) v = ((const half8v*)x)[(size_t)(row0 + r) * 16 + k8];
    #pragma unroll
    for (int q = 0; q < 8; ++q) xs[r][k8 * 8 + q] = (float)v[q];
  }
  __syncthreads();
  int col = t & 31, rp = t >> 5;
  int r0 = rp * 2, r1 = r0 + 1;
  float a0 = 0, a1 = 0;
  for (int k = 0; k < 128; k += 4) {
    float w0 = W[(k + 0) * 32 + col];
    float w1 = W[(k + 1) * 32 + col];
    float w2 = W[(k + 2) * 32 + col];
    float w3 = W[(k + 3) * 32 + col];
    float4 x0 = *(const float4*)&xs[r0][k];
    float4 x1 = *(const float4*)&xs[r1][k];
    a0 += x0.x * w0 + x0.y * w1 + x0.z * w2 + x0.w * w3;
    a1 += x1.x * w0 + x1.y * w1 + x1.z * w2 + x1.w * w3;
  }
  if (row0 + r0 < n) h[(size_t)(row0 + r0) * 32 + col] = (_Float16)a0;
  if (row0 + r1 < n) h[(size_t)(row0 + r1) * 32 + col] = (_Float16)a1;
  sH[r0][col] = a0; sH[r1][col] = a1;
  __syncthreads();
  if (t < 16) {
    int r = t >> 1, which = t & 1;
    if (row0 + r < n) {
      const float* a = which ? a_dst : a_src;
      double s = 0;
      for (int cc = 0; cc < 32; ++cc) s += (double)sH[r][cc] * (double)a[cc];
      (which ? ad_ : as_)[row0 + r] = (float)s;
    }
  }
}

// ---------------- launch 7: GAT layer-2 aggregation + fused mean-pool scatter -------
// No act2 materialization: ELU'd output atomically accumulated into pooled[batch].
__global__ __launch_bounds__(256) void gat_aggr2_pool_kernel(
    const _Float16* __restrict__ feat,  // [n][32] fp16
    const float* __restrict__ as_,      // [n]
    const float* __restrict__ ad_,      // [n]
    const int* __restrict__ rowStart,
    const int* __restrict__ col,
    const float* __restrict__ bias,     // [32]
    const int* __restrict__ batch,
    float* __restrict__ pooled, float* __restrict__ cntG, int n)
{
  constexpr int CHUNK = 16;
  const int t    = threadIdx.x;
  const int wave = t >> 6;
  const int lane = t & 63;
  const int grp  = lane >> 3;
  const int li   = lane & 7;
  const int slot = wave * 8 + grp;
  const int node = blockIdx.x * 32 + slot;

  __shared__ int   s_off[32][CHUNK];
  __shared__ float s_p[32][CHUNK];

  if (node >= n) return;   // safe: wave-private, no block barriers

  const int beg = rowStart[node];
  const int deg = rowStart[node + 1] - beg;

  const float adv = ad_[node];
  const float ps  = expf(leaky02(as_[node] + adv));

  const char* featc = (const char*)feat + (li << 3);   // +8 B per lane, 64 B rows
  const half4v fself = *(const half4v*)(featc + ((size_t)node << 6));
  float a0s = ps * (float)fself.x;
  float a1s = ps * (float)fself.y;
  float a2s = ps * (float)fself.z;
  float a3s = ps * (float)fself.w;
  float den = ps;

  // staging registers: 2 edges per lane
  int   st_s0 = 0, st_s1 = 0;
  float st_q0 = 0.f, st_q1 = 0.f;
  if (deg > 0) {
    int c0 = min(CHUNK, deg);
    if (li < c0)     { st_s0 = col[beg + li];     st_q0 = as_[st_s0]; }
    if (li + 8 < c0) { st_s1 = col[beg + li + 8]; st_q1 = as_[st_s1]; }
  }

  const int nch = (deg + CHUNK - 1) / CHUNK;
  for (int c = 0; c < nch; ++c) {
    const int base = c * CHUNK;
    const int cnt  = min(CHUNK, deg - base);
    if (li < cnt)     { s_off[slot][li]     = st_s0 << 6; s_p[slot][li]     = expf(leaky02(st_q0 + adv)); }
    if (li + 8 < cnt) { s_off[slot][li + 8] = st_s1 << 6; s_p[slot][li + 8] = expf(leaky02(st_q1 + adv)); }
    __builtin_amdgcn_wave_barrier();
    const int nbase = base + CHUNK;
    if (nbase < deg) {
      if (nbase + li < deg)     { st_s0 = col[beg + nbase + li];     st_q0 = as_[st_s0]; }
      if (nbase + li + 8 < deg) { st_s1 = col[beg + nbase + li + 8]; st_q1 = as_[st_s1]; }
    }
    float a0 = 0.f, a1 = 0.f, a2 = 0.f, a3 = 0.f, df = 0.f;
    if (cnt == CHUNK) {
      int off[16];
      #pragma unroll
      for (int j = 0; j < 16; ++j) off[j] = s_off[slot][j];
      half4v r[16];
      #pragma unroll
      for (int j = 0; j < 16; ++j) r[j] = *(const half4v*)(featc + off[j]);
      #pragma unroll
      for (int j = 0; j < 16; ++j) {
        float p = s_p[slot][j];
        a0 += p * (float)r[j].x; a1 += p * (float)r[j].y;
        a2 += p * (float)r[j].z; a3 += p * (float)r[j].w;
        df += p;
      }
    } else {
      for (int j = 0; j < cnt; ++j) {
        int off = s_off[slot][j];
        float p = s_p[slot][j];
        const half4v f = *(const half4v*)(featc + off);
        a0 += p * (float)f.x; a1 += p * (float)f.y;
        a2 += p * (float)f.z; a3 += p * (float)f.w;
        df += p;
      }
    }
    __builtin_amdgcn_wave_barrier();
    a0s += a0; a1s += a1; a2s += a2; a3s += a3;
    den += df;
  }

  const float inv = 1.0f / den;
  const float4 bv = *(const float4*)(bias + 4 * li);
  float o0 = eluf(a0s * inv + bv.x);
  float o1 = eluf(a1s * inv + bv.y);
  float o2 = eluf(a2s * inv + bv.z);
  float o3 = eluf(a3s * inv + bv.w);
  const int g = batch[node];
  float* pp = pooled + (size_t)g * 32 + 4 * li;
  atomicAdd(pp + 0, o0);
  atomicAdd(pp + 1, o1);
  atomicAdd(pp + 2, o2);
  atomicAdd(pp + 3, o3);
  if (li == 0) atomicAdd(&cntG[g], 1.0f);
}

// ---------------- launch 8: classifier ---------------------------------------------
__global__ void classifier_kernel(const float* __restrict__ pooled, const float* __restrict__ cnt,
    const float* __restrict__ Wc1, const float* __restrict__ bc1,
    const float* __restrict__ Wc2, const float* __restrict__ bc2,
    float* __restrict__ outp, int g_total)
{
  int g = blockIdx.x * blockDim.x + threadIdx.x;
  if (g < g_total) {
    float inv = 1.0f / cnt[g];
    float pm[32];
    for (int c = 0; c < 32; ++c) pm[c] = pooled[g * 32 + c] * inv;
    double o = (double)bc2[0];
    for (int j = 0; j < 16; ++j) {
      double z = (double)bc1[j];
      for (int c = 0; c < 32; ++c) z += (double)pm[c] * (double)Wc1[c * 16 + j];
      float zr = (float)z;
      zr = zr > 0.f ? zr : 0.f;
      o += (double)zr * (double)Wc2[j];
    }
    outp[g] = (float)o;
  }
}

// ---------------- launch ------------------------------------------------------------
extern "C" void kernel_launch(void* const* d_in, const int* in_sizes, int n_in,
                              void* d_out, int out_size, void* d_ws, size_t ws_size,
                              hipStream_t stream)
{
  const float* x      = (const float*)d_in[0];
  const int*   ei     = (const int*)d_in[1];
  const int*   batch  = (const int*)d_in[3];
  const float* W1     = (const float*)d_in[4];
  const float* a_src1 = (const float*)d_in[5];
  const float* a_dst1 = (const float*)d_in[6];
  const float* b1     = (const float*)d_in[7];
  const float* W2     = (const float*)d_in[8];
  const float* a_src2 = (const float*)d_in[9];
  const float* a_dst2 = (const float*)d_in[10];
  const float* b2     = (const float*)d_in[11];
  const float* Wc1    = (const float*)d_in[12];
  const float* bc1    = (const float*)d_in[13];
  const float* Wc2    = (const float*)d_in[14];
  const float* bc2    = (const float*)d_in[15];

  const int N = in_sizes[0] / 128;
  const int E = in_sizes[1] / 2;
  const int G = out_size;

  const int* srcv = ei;
  const int* dstv = ei + E;

  char* ws = (char*)d_ws;
  size_t off = 0;
  auto alloc = [&](size_t bytes) -> void* {
    void* p = ws + off;
    off += (bytes + 255) & ~(size_t)255;
    return p;
  };
  const int K  = (N + BUCKET_NODES - 1) >> BUCKET_SHIFT;    // buckets (<= MAX_BUCK)
  const int pb = (E + PART_CHUNK - 1) / PART_CHUNK;         // hist/partition blocks
  const int pbPad = (pb + 63) & ~63;

  _Float16* h1   = (_Float16*)alloc((size_t)N * 128 * 2);   // [N][128]
  _Float16* act1 = (_Float16*)alloc((size_t)N * 128 * 2);   // [N][128]
  _Float16* h2   = (_Float16*)alloc((size_t)N * 32 * 2);    // [N][32]
  float* as1   = (float*)alloc((size_t)N * 4 * 4);          // [N][4]
  float* ad1   = (float*)alloc((size_t)N * 4 * 4);
  float* as2   = (float*)alloc((size_t)N * 4);
  float* ad2   = (float*)alloc((size_t)N * 4);
  int*   rowStart = (int*)alloc((size_t)(N + 1) * 4);
  int*   colv     = (int*)alloc((size_t)E * 4);
  unsigned int* bucketed = (unsigned int*)alloc((size_t)E * 4);
  int*   bucketPartial = (int*)alloc((size_t)MAX_BUCK * pbPad * 4);  // [b][j]
  int*   bucketStart   = (int*)alloc((size_t)MAX_BUCK * 4);
  // ---- zeroed-aux region (contiguous; zeroed by launch-1 hist block 0) ----
  size_t zoff0 = off;
  float* pooled = (float*)alloc((size_t)G * 32 * 4);
  float* cntG   = (float*)alloc((size_t)G * 4);
  size_t zoff1 = off;
  const int zwords = (int)((zoff1 - zoff0) / 4);
  int* zbase = (int*)pooled;

  // 1) fused gemm1 + bucket-hist (+ aux zeroing)
  const int gemmBlocks = (N + 15) / 16;
  gemm1_hist_kernel<<<pb + gemmBlocks, 256, 0, stream>>>(
      x, W1, a_src1, a_dst1, h1, as1, ad1, N,
      dstv, bucketPartial, pbPad, E, K, pb, zbase, zwords);
  // 2) 2-D scan -> per-(bucket,block) offsets + bucketStart
  scan2d_kernel<<<1, 256, 0, stream>>>(bucketPartial, pbPad, bucketStart, pb, K);
  // 3) partition (pure scatter)
  partition_kernel<<<pb, 256, 0, stream>>>(srcv, dstv, bucketStart, bucketPartial, pbPad,
                                           bucketed, E, K);
  // 4) per-bucket fill -> rowStart + col
  fill_csr_kernel<<<K, 256, 0, stream>>>(bucketed, bucketStart, rowStart, colv, N, E, K);
  // 5) layer-1 aggregation
  gat_aggr1_kernel<<<(N + 15) / 16, 256, 0, stream>>>(h1, as1, ad1, rowStart, colv, b1, act1, N);
  // 6) gemm2
  gemm2_kernel<<<(N + 7) / 8, 128, 0, stream>>>(act1, W2, a_src2, a_dst2, h2, as2, ad2, N);
  // 7) layer-2 aggregation + fused mean-pool scatter
  gat_aggr2_pool_kernel<<<(N + 31) / 32, 256, 0, stream>>>(h2, as2, ad2, rowStart, colv, b2,
                                                           batch, pooled, cntG, N);
  // 8) classifier
  classifier_kernel<<<(G + 255) / 256, 256, 0, stream>>>(pooled, cntG, Wc1, bc1, Wc2, bc2,
                                                         (float*)d_out, G);
}

// Round 8
// 432.380 us; speedup vs baseline: 1.2201x; 1.2201x over previous
//
#include <hip/hip_runtime.h>
#include <math.h>

#define BUCKET_SHIFT 7                 // 128 nodes per bucket
#define BUCKET_NODES (1 << BUCKET_SHIFT)
#define MAX_BUCK 512                   // >= ceil(N / BUCKET_NODES)
#define PART_CHUNK 8192
#define PART_EPT 32                    // PART_CHUNK / 256

typedef _Float16 half4v __attribute__((ext_vector_type(4)));
typedef _Float16 half8v __attribute__((ext_vector_type(8)));

__device__ __forceinline__ float leaky02(float x){ return x > 0.f ? x : 0.2f * x; }
__device__ __forceinline__ float eluf(float x){ return x > 0.f ? x : expm1f(x); }

// ---------------- launch 1: gemm1 (16 rows/block, 256 thr) + bucket-hist blocks -----
__global__ __launch_bounds__(256) void gemm1_hist_kernel(
    const float* __restrict__ x, const float* __restrict__ W,
    const float* __restrict__ a_src, const float* __restrict__ a_dst, // flat [128]
    _Float16* __restrict__ h, float* __restrict__ as_, float* __restrict__ ad_, int n,
    const int* __restrict__ dstv, int* __restrict__ bucketPartial, int pbPad,
    int E, int K, int histBlocks,
    int* __restrict__ zbase, int zwords)
{
  const int t = threadIdx.x;
  if (blockIdx.x < histBlocks) {
    // ---- histogram part ----
    __shared__ int hist[MAX_BUCK];
    for (int b = t; b < K; b += 256) hist[b] = 0;
    __syncthreads();
    const int j = blockIdx.x;
    int cbase = j * PART_CHUNK;
    for (int q = 0; q < PART_EPT; ++q) {
      int e = cbase + q * 256 + t;
      if (e < E) atomicAdd(&hist[dstv[e] >> BUCKET_SHIFT], 1);
    }
    __syncthreads();
    for (int b = t; b < K; b += 256)
      bucketPartial[(size_t)b * pbPad + j] = hist[b];
    if (j == 0) {
      for (int i = t; i < zwords; i += 256) zbase[i] = 0;
    }
    return;
  }
  // ---- gemm part ----
  const int g = blockIdx.x - histBlocks;
  const int row0 = g * 16;
  __shared__ float xs[16][128];
  __shared__ float sS[16][128];
  __shared__ float sD[16][128];
  for (int idx = t; idx < 16 * 32; idx += 256) {
    int r = idx >> 5, k4 = idx & 31;
    float4 v = (row0 + r < n) ? ((const float4*)x)[(size_t)(row0 + r) * 32 + k4]
                              : make_float4(0.f, 0.f, 0.f, 0.f);
    *(float4*)&xs[r][k4 * 4] = v;
  }
  __syncthreads();
  const int col = t & 127, hf = t >> 7;
  float acc[8] = {0,0,0,0,0,0,0,0};
  for (int k = 0; k < 128; k += 4) {
    float w0 = W[(k + 0) * 128 + col];
    float w1 = W[(k + 1) * 128 + col];
    float w2 = W[(k + 2) * 128 + col];
    float w3 = W[(k + 3) * 128 + col];
    #pragma unroll
    for (int r = 0; r < 8; ++r) {
      const float4 xv = *(const float4*)&xs[hf * 8 + r][k];
      acc[r] += xv.x * w0 + xv.y * w1 + xv.z * w2 + xv.w * w3;
    }
  }
  float asv = a_src[col], adv = a_dst[col];
  #pragma unroll
  for (int r = 0; r < 8; ++r) {
    int row = hf * 8 + r;
    float hv = acc[r];
    if (row0 + row < n) h[(size_t)(row0 + row) * 128 + col] = (_Float16)hv;
    sS[row][col] = hv * asv;
    sD[row][col] = hv * adv;
  }
  __syncthreads();
  if (t < 128) {
    int r = t >> 3, head = (t >> 1) & 3, which = t & 1;
    if (row0 + r < n) {
      const float (*buf)[128] = which ? sD : sS;
      double s2 = 0;
      for (int cc = 0; cc < 32; ++cc) s2 += (double)buf[r][head * 32 + cc];
      (which ? ad_ : as_)[(row0 + r) * 4 + head] = (float)s2;
    }
  }
}

// ---------------- launch 2: per-bucket parallel scan over chunk counts --------------
// One block per bucket: exclusive scan of partial[b][0..pb) in LDS; total -> bucketStart[b].
__global__ __launch_bounds__(256) void scan_rows_kernel(
    int* __restrict__ partial, int pbPad, int* __restrict__ bucketStart, int pb)
{
  const int b = blockIdx.x;
  const int t = threadIdx.x;
  int* row = partial + (size_t)b * pbPad;
  __shared__ int s[256];
  __shared__ int carry_s;
  if (t == 0) carry_s = 0;
  __syncthreads();
  for (int base = 0; base < pb; base += 256) {
    int v = (base + t < pb) ? row[base + t] : 0;
    s[t] = v;
    __syncthreads();
    for (int off = 1; off < 256; off <<= 1) {
      int xv = (t >= off) ? s[t - off] : 0;
      __syncthreads();
      s[t] += xv;
      __syncthreads();
    }
    int incl = s[t];
    int carry = carry_s;
    if (base + t < pb) row[base + t] = carry + incl - v;   // exclusive
    __syncthreads();
    if (t == 255) carry_s = carry + incl;
    __syncthreads();
  }
  if (t == 0) bucketStart[b] = carry_s;   // row total
}

// ---------------- launch 3: exclusive scan over bucket totals -----------------------
__global__ __launch_bounds__(256) void scan_buckets_kernel(int* __restrict__ arr, int nb) {
  __shared__ int s[256];
  __shared__ int carry_s;
  int t = threadIdx.x;
  if (t == 0) carry_s = 0;
  __syncthreads();
  for (int b = 0; b < nb; b += 256) {
    int v = (b + t < nb) ? arr[b + t] : 0;
    s[t] = v;
    __syncthreads();
    for (int off = 1; off < 256; off <<= 1) {
      int x = (t >= off) ? s[t - off] : 0;
      __syncthreads();
      s[t] += x;
      __syncthreads();
    }
    int incl = s[t];
    int carry = carry_s;
    if (b + t < nb) arr[b + t] = carry + incl - v;   // exclusive
    __syncthreads();
    if (t == 255) carry_s = carry + incl;
    __syncthreads();
  }
}

// ---------------- launch 4: partition — pure scatter, no global atomics -------------
__global__ __launch_bounds__(256) void partition_kernel(
    const int* __restrict__ src, const int* __restrict__ dst,
    const int* __restrict__ bucketStart, const int* __restrict__ pre, int pbPad,
    unsigned int* __restrict__ bucketed, int E, int K)
{
  __shared__ int base_s[MAX_BUCK];
  __shared__ int cur[MAX_BUCK];
  const int j = blockIdx.x;
  for (int b = threadIdx.x; b < K; b += 256) {
    base_s[b] = bucketStart[b] + pre[(size_t)b * pbPad + j];
    cur[b] = 0;
  }
  __syncthreads();
  int cbase = j * PART_CHUNK;
  for (int q = 0; q < PART_EPT; ++q) {
    int e = cbase + q * 256 + threadIdx.x;
    if (e < E) {
      int d = dst[e];
      int b = d >> BUCKET_SHIFT;
      int r = atomicAdd(&cur[b], 1);
      bucketed[base_s[b] + r] =
          ((unsigned int)src[e] << BUCKET_SHIFT) | (unsigned int)(d & (BUCKET_NODES - 1));
    }
  }
}

// ---------------- launch 5: per-bucket LDS hist -> scan -> rowStart -> fine fill ----
__global__ __launch_bounds__(256) void fill_csr_kernel(
    const unsigned int* __restrict__ bucketed, const int* __restrict__ bucketStart,
    int* __restrict__ rowStart, int* __restrict__ col, int n, int E, int K)
{
  int b = blockIdx.x;
  int nodeBase = b << BUCKET_SHIFT;
  int t = threadIdx.x;
  __shared__ int hist[BUCKET_NODES];
  __shared__ int rs[BUCKET_NODES];
  __shared__ int cur[BUCKET_NODES];
  if (t < BUCKET_NODES) hist[t] = 0;
  __syncthreads();
  int bs = bucketStart[b];
  int be = (b + 1 < K) ? bucketStart[b + 1] : E;
  for (int i = bs + t; i < be; i += 256)
    atomicAdd(&hist[bucketed[i] & (BUCKET_NODES - 1)], 1);
  __syncthreads();
  if (t < BUCKET_NODES) rs[t] = hist[t];
  __syncthreads();
  for (int off = 1; off < BUCKET_NODES; off <<= 1) {
    int v = (t < BUCKET_NODES && t >= off) ? rs[t - off] : 0;
    __syncthreads();
    if (t < BUCKET_NODES) rs[t] += v;
    __syncthreads();
  }
  if (t < BUCKET_NODES) {
    int node = nodeBase + t;
    int excl = bs + rs[t] - hist[t];      // exclusive start, absolute
    if (node < n) rowStart[node] = excl;
    rs[t] = excl;
    cur[t] = 0;
  }
  if (b == K - 1 && t == 0) rowStart[n] = E;
  __syncthreads();
  for (int i = bs + t; i < be; i += 256) {
    unsigned int rec = bucketed[i];
    int local = rec & (BUCKET_NODES - 1);
    int pos = rs[local] + atomicAdd(&cur[local], 1);
    col[pos] = (int)(rec >> BUCKET_SHIFT);
  }
}

// ---------------- launch 6: GAT aggregation layer 1 (f32 accumulators) --------------
__global__ __launch_bounds__(256) void gat_aggr1_kernel(
    const _Float16* __restrict__ feat,  // [n][128] fp16
    const float* __restrict__ as_,      // [n][4]
    const float* __restrict__ ad_,      // [n][4]
    const int* __restrict__ rowStart,
    const int* __restrict__ col,
    const float* __restrict__ bias,     // [128]
    _Float16* __restrict__ out, int n)  // [n][128] fp16
{
  constexpr int CHUNK = 16;
  const int t    = threadIdx.x;
  const int wave = t >> 6;
  const int lane = t & 63;
  const int grp  = lane >> 4;
  const int li   = lane & 15;
  const int slot = wave * 4 + grp;
  const int node = blockIdx.x * 16 + slot;
  const int hc   = li >> 2;

  __shared__ int   s_off[16][CHUNK];
  __shared__ float s_p[16][CHUNK * 4];

  if (node >= n) return;   // safe: wave-private, no block barriers

  const int beg = rowStart[node];
  const int deg = rowStart[node + 1] - beg;

  const float4 advv = ((const float4*)ad_)[node];
  const float4 asvv = ((const float4*)as_)[node];
  const float adv[4] = {advv.x, advv.y, advv.z, advv.w};
  float es;
  {
    float e0 = leaky02(asvv.x + adv[0]);
    float e1 = leaky02(asvv.y + adv[1]);
    float e2 = leaky02(asvv.z + adv[2]);
    float e3 = leaky02(asvv.w + adv[3]);
    es = (hc == 0) ? e0 : (hc == 1) ? e1 : (hc == 2) ? e2 : e3;
  }
  const float ps = expf(es);

  const char* featc = (const char*)feat + (li << 4);   // +16 B per lane, 256 B rows
  const half8v fself = *(const half8v*)(featc + ((size_t)node << 8));
  float accf[8];
  #pragma unroll
  for (int q = 0; q < 8; ++q) accf[q] = ps * (float)fself[q];
  float den = ps;

  // staging registers (1 edge per lane)
  int    st_s = 0;
  float4 st_q = make_float4(0.f, 0.f, 0.f, 0.f);
  if (deg > 0 && li < min(CHUNK, deg)) {
    st_s = col[beg + li];
    st_q = ((const float4*)as_)[st_s];
  }

  const int nch = (deg + CHUNK - 1) / CHUNK;
  for (int c = 0; c < nch; ++c) {
    const int base = c * CHUNK;
    const int cnt  = min(CHUNK, deg - base);
    if (li < cnt) {
      s_off[slot][li] = st_s << 8;
      float4 pp;
      pp.x = expf(leaky02(st_q.x + adv[0]));
      pp.y = expf(leaky02(st_q.y + adv[1]));
      pp.z = expf(leaky02(st_q.z + adv[2]));
      pp.w = expf(leaky02(st_q.w + adv[3]));
      *(float4*)&s_p[slot][li * 4] = pp;
    }
    __builtin_amdgcn_wave_barrier();   // staging before consumption
    const int nbase = base + CHUNK;
    if (nbase + li < deg) {
      st_s = col[beg + nbase + li];
      st_q = ((const float4*)as_)[st_s];
    }
    float a[8] = {0,0,0,0,0,0,0,0};
    float df = 0.f;
    if (cnt == CHUNK) {
      int off[16];
      #pragma unroll
      for (int j = 0; j < 16; ++j) off[j] = s_off[slot][j];
      half8v r[16];
      #pragma unroll
      for (int j = 0; j < 16; ++j) r[j] = *(const half8v*)(featc + off[j]);
      #pragma unroll
      for (int j = 0; j < 16; ++j) {
        float p = s_p[slot][j * 4 + hc];
        #pragma unroll
        for (int q = 0; q < 8; ++q) a[q] += p * (float)r[j][q];
        df += p;
      }
    } else {
      for (int j = 0; j < cnt; ++j) {
        int off = s_off[slot][j];
        float p = s_p[slot][j * 4 + hc];
        const half8v f = *(const half8v*)(featc + off);
        #pragma unroll
        for (int q = 0; q < 8; ++q) a[q] += p * (float)f[q];
        df += p;
      }
    }
    __builtin_amdgcn_wave_barrier();   // consumption before next staging
    #pragma unroll
    for (int q = 0; q < 8; ++q) accf[q] += a[q];
    den += df;
  }

  const float4 bv0 = ((const float4*)bias)[2 * li];
  const float4 bv1 = ((const float4*)bias)[2 * li + 1];
  const float bb[8] = {bv0.x, bv0.y, bv0.z, bv0.w, bv1.x, bv1.y, bv1.z, bv1.w};
  const float inv = 1.0f / den;
  half8v ov;
  #pragma unroll
  for (int q = 0; q < 8; ++q)
    ov[q] = (_Float16)eluf(accf[q] * inv + bb[q]);
  *(half8v*)((char*)out + ((size_t)node << 8) + (li << 4)) = ov;
}

// ---------------- launch 7: GEMM2 (N x 128 fp16) @ (128 x 32), fused alphas ---------
__global__ __launch_bounds__(128) void gemm2_kernel(
    const _Float16* __restrict__ x, const float* __restrict__ W,
    const float* __restrict__ a_src, const float* __restrict__ a_dst, // [32]
    _Float16* __restrict__ h, float* __restrict__ as_, float* __restrict__ ad_, int n)
{
  const int t = threadIdx.x;
  const int row0 = blockIdx.x * 8;
  __shared__ float xs[8][128];
  __shared__ float sH[8][32];
  for (int idx = t; idx < 8 * 16; idx += 128) {
    int r = idx >> 4, k8 = idx & 15;
    half8v v;
    #pragma unroll
    for (int q = 0; q < 8; ++q) v[q] = (_Float16)0.f;
    if (row0 + r < n) v = ((const half8v*)x)[(size_t)(row0 + r) * 16 + k8];
    #pragma unroll
    for (int q = 0; q < 8; ++q) xs[r][k8 * 8 + q] = (float)v[q];
  }
  __syncthreads();
  int col = t & 31, rp = t >> 5;
  int r0 = rp * 2, r1 = r0 + 1;
  float a0 = 0, a1 = 0;
  for (int k = 0; k < 128; k += 4) {
    float w0 = W[(k + 0) * 32 + col];
    float w1 = W[(k + 1) * 32 + col];
    float w2 = W[(k + 2) * 32 + col];
    float w3 = W[(k + 3) * 32 + col];
    float4 x0 = *(const float4*)&xs[r0][k];
    float4 x1 = *(const float4*)&xs[r1][k];
    a0 += x0.x * w0 + x0.y * w1 + x0.z * w2 + x0.w * w3;
    a1 += x1.x * w0 + x1.y * w1 + x1.z * w2 + x1.w * w3;
  }
  if (row0 + r0 < n) h[(size_t)(row0 + r0) * 32 + col] = (_Float16)a0;
  if (row0 + r1 < n) h[(size_t)(row0 + r1) * 32 + col] = (_Float16)a1;
  sH[r0][col] = a0; sH[r1][col] = a1;
  __syncthreads();
  if (t < 16) {
    int r = t >> 1, which = t & 1;
    if (row0 + r < n) {
      const float* a = which ? a_dst : a_src;
      double s = 0;
      for (int cc = 0; cc < 32; ++cc) s += (double)sH[r][cc] * (double)a[cc];
      (which ? ad_ : as_)[row0 + r] = (float)s;
    }
  }
}

// ---------------- launch 8: GAT layer-2 aggregation + fused mean-pool scatter -------
__global__ __launch_bounds__(256) void gat_aggr2_pool_kernel(
    const _Float16* __restrict__ feat,  // [n][32] fp16
    const float* __restrict__ as_,      // [n]
    const float* __restrict__ ad_,      // [n]
    const int* __restrict__ rowStart,
    const int* __restrict__ col,
    const float* __restrict__ bias,     // [32]
    const int* __restrict__ batch,
    float* __restrict__ pooled, float* __restrict__ cntG, int n)
{
  constexpr int CHUNK = 16;
  const int t    = threadIdx.x;
  const int wave = t >> 6;
  const int lane = t & 63;
  const int grp  = lane >> 3;
  const int li   = lane & 7;
  const int slot = wave * 8 + grp;
  const int node = blockIdx.x * 32 + slot;

  __shared__ int   s_off[32][CHUNK];
  __shared__ float s_p[32][CHUNK];

  if (node >= n) return;   // safe: wave-private, no block barriers

  const int beg = rowStart[node];
  const int deg = rowStart[node + 1] - beg;

  const float adv = ad_[node];
  const float ps  = expf(leaky02(as_[node] + adv));

  const char* featc = (const char*)feat + (li << 3);   // +8 B per lane, 64 B rows
  const half4v fself = *(const half4v*)(featc + ((size_t)node << 6));
  float a0s = ps * (float)fself.x;
  float a1s = ps * (float)fself.y;
  float a2s = ps * (float)fself.z;
  float a3s = ps * (float)fself.w;
  float den = ps;

  // staging registers: 2 edges per lane
  int   st_s0 = 0, st_s1 = 0;
  float st_q0 = 0.f, st_q1 = 0.f;
  if (deg > 0) {
    int c0 = min(CHUNK, deg);
    if (li < c0)     { st_s0 = col[beg + li];     st_q0 = as_[st_s0]; }
    if (li + 8 < c0) { st_s1 = col[beg + li + 8]; st_q1 = as_[st_s1]; }
  }

  const int nch = (deg + CHUNK - 1) / CHUNK;
  for (int c = 0; c < nch; ++c) {
    const int base = c * CHUNK;
    const int cnt  = min(CHUNK, deg - base);
    if (li < cnt)     { s_off[slot][li]     = st_s0 << 6; s_p[slot][li]     = expf(leaky02(st_q0 + adv)); }
    if (li + 8 < cnt) { s_off[slot][li + 8] = st_s1 << 6; s_p[slot][li + 8] = expf(leaky02(st_q1 + adv)); }
    __builtin_amdgcn_wave_barrier();
    const int nbase = base + CHUNK;
    if (nbase < deg) {
      if (nbase + li < deg)     { st_s0 = col[beg + nbase + li];     st_q0 = as_[st_s0]; }
      if (nbase + li + 8 < deg) { st_s1 = col[beg + nbase + li + 8]; st_q1 = as_[st_s1]; }
    }
    float a0 = 0.f, a1 = 0.f, a2 = 0.f, a3 = 0.f, df = 0.f;
    if (cnt == CHUNK) {
      int off[16];
      #pragma unroll
      for (int j = 0; j < 16; ++j) off[j] = s_off[slot][j];
      half4v r[16];
      #pragma unroll
      for (int j = 0; j < 16; ++j) r[j] = *(const half4v*)(featc + off[j]);
      #pragma unroll
      for (int j = 0; j < 16; ++j) {
        float p = s_p[slot][j];
        a0 += p * (float)r[j].x; a1 += p * (float)r[j].y;
        a2 += p * (float)r[j].z; a3 += p * (float)r[j].w;
        df += p;
      }
    } else {
      for (int j = 0; j < cnt; ++j) {
        int off = s_off[slot][j];
        float p = s_p[slot][j];
        const half4v f = *(const half4v*)(featc + off);
        a0 += p * (float)f.x; a1 += p * (float)f.y;
        a2 += p * (float)f.z; a3 += p * (float)f.w;
        df += p;
      }
    }
    __builtin_amdgcn_wave_barrier();
    a0s += a0; a1s += a1; a2s += a2; a3s += a3;
    den += df;
  }

  const float inv = 1.0f / den;
  const float4 bv = *(const float4*)(bias + 4 * li);
  float o0 = eluf(a0s * inv + bv.x);
  float o1 = eluf(a1s * inv + bv.y);
  float o2 = eluf(a2s * inv + bv.z);
  float o3 = eluf(a3s * inv + bv.w);
  const int g = batch[node];
  float* pp = pooled + (size_t)g * 32 + 4 * li;
  atomicAdd(pp + 0, o0);
  atomicAdd(pp + 1, o1);
  atomicAdd(pp + 2, o2);
  atomicAdd(pp + 3, o3);
  if (li == 0) atomicAdd(&cntG[g], 1.0f);
}

// ---------------- launch 9: classifier ---------------------------------------------
__global__ void classifier_kernel(const float* __restrict__ pooled, const float* __restrict__ cnt,
    const float* __restrict__ Wc1, const float* __restrict__ bc1,
    const float* __restrict__ Wc2, const float* __restrict__ bc2,
    float* __restrict__ outp, int g_total)
{
  int g = blockIdx.x * blockDim.x + threadIdx.x;
  if (g < g_total) {
    float inv = 1.0f / cnt[g];
    float pm[32];
    for (int c = 0; c < 32; ++c) pm[c] = pooled[g * 32 + c] * inv;
    double o = (double)bc2[0];
    for (int j = 0; j < 16; ++j) {
      double z = (double)bc1[j];
      for (int c = 0; c < 32; ++c) z += (double)pm[c] * (double)Wc1[c * 16 + j];
      float zr = (float)z;
      zr = zr > 0.f ? zr : 0.f;
      o += (double)zr * (double)Wc2[j];
    }
    outp[g] = (float)o;
  }
}

// ---------------- launch ------------------------------------------------------------
extern "C" void kernel_launch(void* const* d_in, const int* in_sizes, int n_in,
                              void* d_out, int out_size, void* d_ws, size_t ws_size,
                              hipStream_t stream)
{
  const float* x      = (const float*)d_in[0];
  const int*   ei     = (const int*)d_in[1];
  const int*   batch  = (const int*)d_in[3];
  const float* W1     = (const float*)d_in[4];
  const float* a_src1 = (const float*)d_in[5];
  const float* a_dst1 = (const float*)d_in[6];
  const float* b1     = (const float*)d_in[7];
  const float* W2     = (const float*)d_in[8];
  const float* a_src2 = (const float*)d_in[9];
  const float* a_dst2 = (const float*)d_in[10];
  const float* b2     = (const float*)d_in[11];
  const float* Wc1    = (const float*)d_in[12];
  const float* bc1    = (const float*)d_in[13];
  const float* Wc2    = (const float*)d_in[14];
  const float* bc2    = (const float*)d_in[15];

  const int N = in_sizes[0] / 128;
  const int E = in_sizes[1] / 2;
  const int G = out_size;

  const int* srcv = ei;
  const int* dstv = ei + E;

  char* ws = (char*)d_ws;
  size_t off = 0;
  auto alloc = [&](size_t bytes) -> void* {
    void* p = ws + off;
    off += (bytes + 255) & ~(size_t)255;
    return p;
  };
  const int K  = (N + BUCKET_NODES - 1) >> BUCKET_SHIFT;    // buckets (<= MAX_BUCK)
  const int pb = (E + PART_CHUNK - 1) / PART_CHUNK;         // hist/partition blocks
  const int pbPad = (pb + 63) & ~63;

  _Float16* h1   = (_Float16*)alloc((size_t)N * 128 * 2);   // [N][128]
  _Float16* act1 = (_Float16*)alloc((size_t)N * 128 * 2);   // [N][128]
  _Float16* h2   = (_Float16*)alloc((size_t)N * 32 * 2);    // [N][32]
  float* as1   = (float*)alloc((size_t)N * 4 * 4);          // [N][4]
  float* ad1   = (float*)alloc((size_t)N * 4 * 4);
  float* as2   = (float*)alloc((size_t)N * 4);
  float* ad2   = (float*)alloc((size_t)N * 4);
  int*   rowStart = (int*)alloc((size_t)(N + 1) * 4);
  int*   colv     = (int*)alloc((size_t)E * 4);
  unsigned int* bucketed = (unsigned int*)alloc((size_t)E * 4);
  int*   bucketPartial = (int*)alloc((size_t)MAX_BUCK * pbPad * 4);  // [b][j]
  int*   bucketStart   = (int*)alloc((size_t)MAX_BUCK * 4);
  // ---- zeroed-aux region (contiguous; zeroed by launch-1 hist block 0) ----
  size_t zoff0 = off;
  float* pooled = (float*)alloc((size_t)G * 32 * 4);
  float* cntG   = (float*)alloc((size_t)G * 4);
  size_t zoff1 = off;
  const int zwords = (int)((zoff1 - zoff0) / 4);
  int* zbase = (int*)pooled;

  // 1) fused gemm1 + bucket-hist (+ aux zeroing)
  const int gemmBlocks = (N + 15) / 16;
  gemm1_hist_kernel<<<pb + gemmBlocks, 256, 0, stream>>>(
      x, W1, a_src1, a_dst1, h1, as1, ad1, N,
      dstv, bucketPartial, pbPad, E, K, pb, zbase, zwords);
  // 2) per-bucket parallel scan of chunk counts (totals -> bucketStart)
  scan_rows_kernel<<<K, 256, 0, stream>>>(bucketPartial, pbPad, bucketStart, pb);
  // 3) exclusive scan over bucket totals
  scan_buckets_kernel<<<1, 256, 0, stream>>>(bucketStart, K);
  // 4) partition (pure scatter)
  partition_kernel<<<pb, 256, 0, stream>>>(srcv, dstv, bucketStart, bucketPartial, pbPad,
                                           bucketed, E, K);
  // 5) per-bucket fill -> rowStart + col
  fill_csr_kernel<<<K, 256, 0, stream>>>(bucketed, bucketStart, rowStart, colv, N, E, K);
  // 6) layer-1 aggregation
  gat_aggr1_kernel<<<(N + 15) / 16, 256, 0, stream>>>(h1, as1, ad1, rowStart, colv, b1, act1, N);
  // 7) gemm2
  gemm2_kernel<<<(N + 7) / 8, 128, 0, stream>>>(act1, W2, a_src2, a_dst2, h2, as2, ad2, N);
  // 8) layer-2 aggregation + fused mean-pool scatter
  gat_aggr2_pool_kernel<<<(N + 31) / 32, 256, 0, stream>>>(h2, as2, ad2, rowStart, colv, b2,
                                                           batch, pooled, cntG, N);
  // 9) classifier
  classifier_kernel<<<(G + 255) / 256, 256, 0, stream>>>(pooled, cntG, Wc1, bc1, Wc2, bc2,
                                                         (float*)d_out, G);
}

// Round 9
// 364.133 us; speedup vs baseline: 1.4488x; 1.1874x over previous
//
#include <hip/hip_runtime.h>
#include <math.h>

#define BUCKET_SHIFT 7                 // 128 nodes per bucket
#define BUCKET_NODES (1 << BUCKET_SHIFT)
#define MAX_BUCK 512                   // >= ceil(N / BUCKET_NODES)
#define PART_CHUNK 8192
#define PART_EPT 32                    // PART_CHUNK / 256

typedef _Float16 half4v __attribute__((ext_vector_type(4)));
typedef _Float16 half8v __attribute__((ext_vector_type(8)));

__device__ __forceinline__ float leaky02(float x){ return x > 0.f ? x : 0.2f * x; }
__device__ __forceinline__ float eluf(float x){ return x > 0.f ? x : expm1f(x); }

// ---------------- launch 1: gemm1 (16 rows/block, 256 thr) + bucket-hist blocks -----
__global__ __launch_bounds__(256) void gemm1_hist_kernel(
    const float* __restrict__ x, const float* __restrict__ W,
    const float* __restrict__ a_src, const float* __restrict__ a_dst, // flat [128]
    _Float16* __restrict__ h, float* __restrict__ as_, float* __restrict__ ad_, int n,
    const int* __restrict__ dstv, int* __restrict__ bucketPartial, int pbPad,
    int E, int K, int histBlocks,
    int* __restrict__ zbase, int zwords)
{
  const int t = threadIdx.x;
  if (blockIdx.x < histBlocks) {
    // ---- histogram part ----
    __shared__ int hist[MAX_BUCK];
    for (int b = t; b < K; b += 256) hist[b] = 0;
    __syncthreads();
    const int j = blockIdx.x;
    int cbase = j * PART_CHUNK;
    for (int q = 0; q < PART_EPT; ++q) {
      int e = cbase + q * 256 + t;
      if (e < E) atomicAdd(&hist[dstv[e] >> BUCKET_SHIFT], 1);
    }
    __syncthreads();
    for (int b = t; b < K; b += 256)
      bucketPartial[(size_t)b * pbPad + j] = hist[b];
    if (j == 0) {
      for (int i = t; i < zwords; i += 256) zbase[i] = 0;
    }
    return;
  }
  // ---- gemm part ----
  const int g = blockIdx.x - histBlocks;
  const int row0 = g * 16;
  __shared__ float xs[16][128];
  __shared__ float sS[16][128];
  __shared__ float sD[16][128];
  for (int idx = t; idx < 16 * 32; idx += 256) {
    int r = idx >> 5, k4 = idx & 31;
    float4 v = (row0 + r < n) ? ((const float4*)x)[(size_t)(row0 + r) * 32 + k4]
                              : make_float4(0.f, 0.f, 0.f, 0.f);
    *(float4*)&xs[r][k4 * 4] = v;
  }
  __syncthreads();
  const int col = t & 127, hf = t >> 7;
  float acc[8] = {0,0,0,0,0,0,0,0};
  for (int k = 0; k < 128; k += 4) {
    float w0 = W[(k + 0) * 128 + col];
    float w1 = W[(k + 1) * 128 + col];
    float w2 = W[(k + 2) * 128 + col];
    float w3 = W[(k + 3) * 128 + col];
    #pragma unroll
    for (int r = 0; r < 8; ++r) {
      const float4 xv = *(const float4*)&xs[hf * 8 + r][k];
      acc[r] += xv.x * w0 + xv.y * w1 + xv.z * w2 + xv.w * w3;
    }
  }
  float asv = a_src[col], adv = a_dst[col];
  #pragma unroll
  for (int r = 0; r < 8; ++r) {
    int row = hf * 8 + r;
    float hv = acc[r];
    if (row0 + row < n) h[(size_t)(row0 + row) * 128 + col] = (_Float16)hv;
    sS[row][col] = hv * asv;
    sD[row][col] = hv * adv;
  }
  __syncthreads();
  if (t < 128) {
    int r = t >> 3, head = (t >> 1) & 3, which = t & 1;
    if (row0 + r < n) {
      const float (*buf)[128] = which ? sD : sS;
      double s2 = 0;
      for (int cc = 0; cc < 32; ++cc) s2 += (double)buf[r][head * 32 + cc];
      (which ? ad_ : as_)[(row0 + r) * 4 + head] = (float)s2;
    }
  }
}

// ---------------- launch 2: per-bucket parallel scan over chunk counts --------------
__global__ __launch_bounds__(256) void scan_rows_kernel(
    int* __restrict__ partial, int pbPad, int* __restrict__ bucketStart, int pb)
{
  const int b = blockIdx.x;
  const int t = threadIdx.x;
  int* row = partial + (size_t)b * pbPad;
  __shared__ int s[256];
  __shared__ int carry_s;
  if (t == 0) carry_s = 0;
  __syncthreads();
  for (int base = 0; base < pb; base += 256) {
    int v = (base + t < pb) ? row[base + t] : 0;
    s[t] = v;
    __syncthreads();
    for (int off = 1; off < 256; off <<= 1) {
      int xv = (t >= off) ? s[t - off] : 0;
      __syncthreads();
      s[t] += xv;
      __syncthreads();
    }
    int incl = s[t];
    int carry = carry_s;
    if (base + t < pb) row[base + t] = carry + incl - v;   // exclusive
    __syncthreads();
    if (t == 255) carry_s = carry + incl;
    __syncthreads();
  }
  if (t == 0) bucketStart[b] = carry_s;   // row total
}

// ---------------- launch 3: exclusive scan over bucket totals -----------------------
__global__ __launch_bounds__(256) void scan_buckets_kernel(int* __restrict__ arr, int nb) {
  __shared__ int s[256];
  __shared__ int carry_s;
  int t = threadIdx.x;
  if (t == 0) carry_s = 0;
  __syncthreads();
  for (int b = 0; b < nb; b += 256) {
    int v = (b + t < nb) ? arr[b + t] : 0;
    s[t] = v;
    __syncthreads();
    for (int off = 1; off < 256; off <<= 1) {
      int x = (t >= off) ? s[t - off] : 0;
      __syncthreads();
      s[t] += x;
      __syncthreads();
    }
    int incl = s[t];
    int carry = carry_s;
    if (b + t < nb) arr[b + t] = carry + incl - v;   // exclusive
    __syncthreads();
    if (t == 255) carry_s = carry + incl;
    __syncthreads();
  }
}

// ---------------- launch 4: partition — pure scatter, no global atomics -------------
__global__ __launch_bounds__(256) void partition_kernel(
    const int* __restrict__ src, const int* __restrict__ dst,
    const int* __restrict__ bucketStart, const int* __restrict__ pre, int pbPad,
    unsigned int* __restrict__ bucketed, int E, int K)
{
  __shared__ int base_s[MAX_BUCK];
  __shared__ int cur[MAX_BUCK];
  const int j = blockIdx.x;
  for (int b = threadIdx.x; b < K; b += 256) {
    base_s[b] = bucketStart[b] + pre[(size_t)b * pbPad + j];
    cur[b] = 0;
  }
  __syncthreads();
  int cbase = j * PART_CHUNK;
  for (int q = 0; q < PART_EPT; ++q) {
    int e = cbase + q * 256 + threadIdx.x;
    if (e < E) {
      int d = dst[e];
      int b = d >> BUCKET_SHIFT;
      int r = atomicAdd(&cur[b], 1);
      bucketed[base_s[b] + r] =
          ((unsigned int)src[e] << BUCKET_SHIFT) | (unsigned int)(d & (BUCKET_NODES - 1));
    }
  }
}

// ---------------- launch 5: per-bucket LDS hist -> scan -> rowStart -> fine fill ----
__global__ __launch_bounds__(256) void fill_csr_kernel(
    const unsigned int* __restrict__ bucketed, const int* __restrict__ bucketStart,
    int* __restrict__ rowStart, int* __restrict__ col, int n, int E, int K)
{
  int b = blockIdx.x;
  int nodeBase = b << BUCKET_SHIFT;
  int t = threadIdx.x;
  __shared__ int hist[BUCKET_NODES];
  __shared__ int rs[BUCKET_NODES];
  __shared__ int cur[BUCKET_NODES];
  if (t < BUCKET_NODES) hist[t] = 0;
  __syncthreads();
  int bs = bucketStart[b];
  int be = (b + 1 < K) ? bucketStart[b + 1] : E;
  for (int i = bs + t; i < be; i += 256)
    atomicAdd(&hist[bucketed[i] & (BUCKET_NODES - 1)], 1);
  __syncthreads();
  if (t < BUCKET_NODES) rs[t] = hist[t];
  __syncthreads();
  for (int off = 1; off < BUCKET_NODES; off <<= 1) {
    int v = (t < BUCKET_NODES && t >= off) ? rs[t - off] : 0;
    __syncthreads();
    if (t < BUCKET_NODES) rs[t] += v;
    __syncthreads();
  }
  if (t < BUCKET_NODES) {
    int node = nodeBase + t;
    int excl = bs + rs[t] - hist[t];      // exclusive start, absolute
    if (node < n) rowStart[node] = excl;
    rs[t] = excl;
    cur[t] = 0;
  }
  if (b == K - 1 && t == 0) rowStart[n] = E;
  __syncthreads();
  for (int i = bs + t; i < be; i += 256) {
    unsigned int rec = bucketed[i];
    int local = rec & (BUCKET_NODES - 1);
    int pos = rs[local] + atomicAdd(&cur[local], 1);
    col[pos] = (int)(rec >> BUCKET_SHIFT);
  }
}

// ---------------- launch 6: GAT aggregation layer 1 (f32 accumulators) --------------
__global__ __launch_bounds__(256) void gat_aggr1_kernel(
    const _Float16* __restrict__ feat,  // [n][128] fp16
    const float* __restrict__ as_,      // [n][4]
    const float* __restrict__ ad_,      // [n][4]
    const int* __restrict__ rowStart,
    const int* __restrict__ col,
    const float* __restrict__ bias,     // [128]
    _Float16* __restrict__ out, int n)  // [n][128] fp16
{
  constexpr int CHUNK = 16;
  const int t    = threadIdx.x;
  const int wave = t >> 6;
  const int lane = t & 63;
  const int grp  = lane >> 4;
  const int li   = lane & 15;
  const int slot = wave * 4 + grp;
  const int node = blockIdx.x * 16 + slot;
  const int hc   = li >> 2;

  __shared__ int   s_off[16][CHUNK];
  __shared__ float s_p[16][CHUNK * 4];

  if (node >= n) return;   // safe: wave-private, no block barriers

  const int beg = rowStart[node];
  const int deg = rowStart[node + 1] - beg;

  const float4 advv = ((const float4*)ad_)[node];
  const float4 asvv = ((const float4*)as_)[node];
  const float adv[4] = {advv.x, advv.y, advv.z, advv.w};
  float es;
  {
    float e0 = leaky02(asvv.x + adv[0]);
    float e1 = leaky02(asvv.y + adv[1]);
    float e2 = leaky02(asvv.z + adv[2]);
    float e3 = leaky02(asvv.w + adv[3]);
    es = (hc == 0) ? e0 : (hc == 1) ? e1 : (hc == 2) ? e2 : e3;
  }
  const float ps = expf(es);

  const char* featc = (const char*)feat + (li << 4);   // +16 B per lane, 256 B rows
  const half8v fself = *(const half8v*)(featc + ((size_t)node << 8));
  float accf[8];
  #pragma unroll
  for (int q = 0; q < 8; ++q) accf[q] = ps * (float)fself[q];
  float den = ps;

  // staging registers (1 edge per lane)
  int    st_s = 0;
  float4 st_q = make_float4(0.f, 0.f, 0.f, 0.f);
  if (deg > 0 && li < min(CHUNK, deg)) {
    st_s = col[beg + li];
    st_q = ((const float4*)as_)[st_s];
  }

  const int nch = (deg + CHUNK - 1) / CHUNK;
  for (int c = 0; c < nch; ++c) {
    const int base = c * CHUNK;
    const int cnt  = min(CHUNK, deg - base);
    if (li < cnt) {
      s_off[slot][li] = st_s << 8;
      float4 pp;
      pp.x = expf(leaky02(st_q.x + adv[0]));
      pp.y = expf(leaky02(st_q.y + adv[1]));
      pp.z = expf(leaky02(st_q.z + adv[2]));
      pp.w = expf(leaky02(st_q.w + adv[3]));
      *(float4*)&s_p[slot][li * 4] = pp;
    }
    __builtin_amdgcn_wave_barrier();   // staging before consumption
    const int nbase = base + CHUNK;
    if (nbase + li < deg) {
      st_s = col[beg + nbase + li];
      st_q = ((const float4*)as_)[st_s];
    }
    float a[8] = {0,0,0,0,0,0,0,0};
    float df = 0.f;
    if (cnt == CHUNK) {
      int off[16];
      #pragma unroll
      for (int j = 0; j < 16; ++j) off[j] = s_off[slot][j];
      half8v r[16];
      #pragma unroll
      for (int j = 0; j < 16; ++j) r[j] = *(const half8v*)(featc + off[j]);
      #pragma unroll
      for (int j = 0; j < 16; ++j) {
        float p = s_p[slot][j * 4 + hc];
        #pragma unroll
        for (int q = 0; q < 8; ++q) a[q] += p * (float)r[j][q];
        df += p;
      }
    } else {
      for (int j = 0; j < cnt; ++j) {
        int off = s_off[slot][j];
        float p = s_p[slot][j * 4 + hc];
        const half8v f = *(const half8v*)(featc + off);
        #pragma unroll
        for (int q = 0; q < 8; ++q) a[q] += p * (float)f[q];
        df += p;
      }
    }
    __builtin_amdgcn_wave_barrier();   // consumption before next staging
    #pragma unroll
    for (int q = 0; q < 8; ++q) accf[q] += a[q];
    den += df;
  }

  const float4 bv0 = ((const float4*)bias)[2 * li];
  const float4 bv1 = ((const float4*)bias)[2 * li + 1];
  const float bb[8] = {bv0.x, bv0.y, bv0.z, bv0.w, bv1.x, bv1.y, bv1.z, bv1.w};
  const float inv = 1.0f / den;
  half8v ov;
  #pragma unroll
  for (int q = 0; q < 8; ++q)
    ov[q] = (_Float16)eluf(accf[q] * inv + bb[q]);
  *(half8v*)((char*)out + ((size_t)node << 8) + (li << 4)) = ov;
}

// ---------------- launch 7: GEMM2 (N x 128 fp16) @ (128 x 32), fused alphas ---------
__global__ __launch_bounds__(128) void gemm2_kernel(
    const _Float16* __restrict__ x, const float* __restrict__ W,
    const float* __restrict__ a_src, const float* __restrict__ a_dst, // [32]
    _Float16* __restrict__ h, float* __restrict__ as_, float* __restrict__ ad_, int n)
{
  const int t = threadIdx.x;
  const int row0 = blockIdx.x * 8;
  __shared__ float xs[8][128];
  __shared__ float sH[8][32];
  for (int idx = t; idx < 8 * 16; idx += 128) {
    int r = idx >> 4, k8 = idx & 15;
    half8v v;
    #pragma unroll
    for (int q = 0; q < 8; ++q) v[q] = (_Float16)0.f;
    if (row0 + r < n) v = ((const half8v*)x)[(size_t)(row0 + r) * 16 + k8];
    #pragma unroll
    for (int q = 0; q < 8; ++q) xs[r][k8 * 8 + q] = (float)v[q];
  }
  __syncthreads();
  int col = t & 31, rp = t >> 5;
  int r0 = rp * 2, r1 = r0 + 1;
  float a0 = 0, a1 = 0;
  for (int k = 0; k < 128; k += 4) {
    float w0 = W[(k + 0) * 32 + col];
    float w1 = W[(k + 1) * 32 + col];
    float w2 = W[(k + 2) * 32 + col];
    float w3 = W[(k + 3) * 32 + col];
    float4 x0 = *(const float4*)&xs[r0][k];
    float4 x1 = *(const float4*)&xs[r1][k];
    a0 += x0.x * w0 + x0.y * w1 + x0.z * w2 + x0.w * w3;
    a1 += x1.x * w0 + x1.y * w1 + x1.z * w2 + x1.w * w3;
  }
  if (row0 + r0 < n) h[(size_t)(row0 + r0) * 32 + col] = (_Float16)a0;
  if (row0 + r1 < n) h[(size_t)(row0 + r1) * 32 + col] = (_Float16)a1;
  sH[r0][col] = a0; sH[r1][col] = a1;
  __syncthreads();
  if (t < 16) {
    int r = t >> 1, which = t & 1;
    if (row0 + r < n) {
      const float* a = which ? a_dst : a_src;
      double s = 0;
      for (int cc = 0; cc < 32; ++cc) s += (double)sH[r][cc] * (double)a[cc];
      (which ? ad_ : as_)[row0 + r] = (float)s;
    }
  }
}

// ---------------- launch 8: GAT aggregation layer 2 (f32 accumulators, f32 out) -----
__global__ __launch_bounds__(256) void gat_aggr2_kernel(
    const _Float16* __restrict__ feat,  // [n][32] fp16
    const float* __restrict__ as_,      // [n]
    const float* __restrict__ ad_,      // [n]
    const int* __restrict__ rowStart,
    const int* __restrict__ col,
    const float* __restrict__ bias,     // [32]
    float* __restrict__ out, int n)     // [n][32] f32
{
  constexpr int CHUNK = 16;
  const int t    = threadIdx.x;
  const int wave = t >> 6;
  const int lane = t & 63;
  const int grp  = lane >> 3;
  const int li   = lane & 7;
  const int slot = wave * 8 + grp;
  const int node = blockIdx.x * 32 + slot;

  __shared__ int   s_off[32][CHUNK];
  __shared__ float s_p[32][CHUNK];

  if (node >= n) return;   // safe: wave-private, no block barriers

  const int beg = rowStart[node];
  const int deg = rowStart[node + 1] - beg;

  const float adv = ad_[node];
  const float ps  = expf(leaky02(as_[node] + adv));

  const char* featc = (const char*)feat + (li << 3);   // +8 B per lane, 64 B rows
  const half4v fself = *(const half4v*)(featc + ((size_t)node << 6));
  float a0s = ps * (float)fself.x;
  float a1s = ps * (float)fself.y;
  float a2s = ps * (float)fself.z;
  float a3s = ps * (float)fself.w;
  float den = ps;

  // staging registers: 2 edges per lane
  int   st_s0 = 0, st_s1 = 0;
  float st_q0 = 0.f, st_q1 = 0.f;
  if (deg > 0) {
    int c0 = min(CHUNK, deg);
    if (li < c0)     { st_s0 = col[beg + li];     st_q0 = as_[st_s0]; }
    if (li + 8 < c0) { st_s1 = col[beg + li + 8]; st_q1 = as_[st_s1]; }
  }

  const int nch = (deg + CHUNK - 1) / CHUNK;
  for (int c = 0; c < nch; ++c) {
    const int base = c * CHUNK;
    const int cnt  = min(CHUNK, deg - base);
    if (li < cnt)     { s_off[slot][li]     = st_s0 << 6; s_p[slot][li]     = expf(leaky02(st_q0 + adv)); }
    if (li + 8 < cnt) { s_off[slot][li + 8] = st_s1 << 6; s_p[slot][li + 8] = expf(leaky02(st_q1 + adv)); }
    __builtin_amdgcn_wave_barrier();
    const int nbase = base + CHUNK;
    if (nbase < deg) {
      if (nbase + li < deg)     { st_s0 = col[beg + nbase + li];     st_q0 = as_[st_s0]; }
      if (nbase + li + 8 < deg) { st_s1 = col[beg + nbase + li + 8]; st_q1 = as_[st_s1]; }
    }
    float a0 = 0.f, a1 = 0.f, a2 = 0.f, a3 = 0.f, df = 0.f;
    if (cnt == CHUNK) {
      int off[16];
      #pragma unroll
      for (int j = 0; j < 16; ++j) off[j] = s_off[slot][j];
      half4v r[16];
      #pragma unroll
      for (int j = 0; j < 16; ++j) r[j] = *(const half4v*)(featc + off[j]);
      #pragma unroll
      for (int j = 0; j < 16; ++j) {
        float p = s_p[slot][j];
        a0 += p * (float)r[j].x; a1 += p * (float)r[j].y;
        a2 += p * (float)r[j].z; a3 += p * (float)r[j].w;
        df += p;
      }
    } else {
      for (int j = 0; j < cnt; ++j) {
        int off = s_off[slot][j];
        float p = s_p[slot][j];
        const half4v f = *(const half4v*)(featc + off);
        a0 += p * (float)f.x; a1 += p * (float)f.y;
        a2 += p * (float)f.z; a3 += p * (float)f.w;
        df += p;
      }
    }
    __builtin_amdgcn_wave_barrier();
    a0s += a0; a1s += a1; a2s += a2; a3s += a3;
    den += df;
  }

  const float inv = 1.0f / den;
  const float4 bv = *(const float4*)(bias + 4 * li);
  float4 o;
  o.x = eluf(a0s * inv + bv.x);
  o.y = eluf(a1s * inv + bv.y);
  o.z = eluf(a2s * inv + bv.z);
  o.w = eluf(a3s * inv + bv.w);
  *(float4*)(out + (size_t)node * 32 + 4 * li) = o;
}

// ---------------- launch 9: pooling (batch is sorted: run-length flush) -------------
__global__ __launch_bounds__(256) void pool_kernel(const float* __restrict__ act2,
    const int* __restrict__ batch, float* __restrict__ pooled,
    float* __restrict__ cnt, int n)
{
  int t = threadIdx.x;
  int c = t & 31, r = t >> 5;
  int n0 = blockIdx.x * 64 + r * 8;
  float run = 0.f; int gcur = -1; int len = 0;
  for (int i = 0; i < 8; ++i) {
    int nd = n0 + i;
    if (nd >= n) break;
    int gb = batch[nd];
    if (gb != gcur) {
      if (gcur >= 0) {
        atomicAdd(&pooled[gcur * 32 + c], run);
        if (c == 0) atomicAdd(&cnt[gcur], (float)len);
      }
      gcur = gb; run = 0.f; len = 0;
    }
    run += act2[(size_t)nd * 32 + c];
    len++;
  }
  if (gcur >= 0) {
    atomicAdd(&pooled[gcur * 32 + c], run);
    if (c == 0) atomicAdd(&cnt[gcur], (float)len);
  }
}

// ---------------- launch 10: classifier ---------------------------------------------
__global__ void classifier_kernel(const float* __restrict__ pooled, const float* __restrict__ cnt,
    const float* __restrict__ Wc1, const float* __restrict__ bc1,
    const float* __restrict__ Wc2, const float* __restrict__ bc2,
    float* __restrict__ outp, int g_total)
{
  int g = blockIdx.x * blockDim.x + threadIdx.x;
  if (g < g_total) {
    float inv = 1.0f / cnt[g];
    float pm[32];
    for (int c = 0; c < 32; ++c) pm[c] = pooled[g * 32 + c] * inv;
    double o = (double)bc2[0];
    for (int j = 0; j < 16; ++j) {
      double z = (double)bc1[j];
      for (int c = 0; c < 32; ++c) z += (double)pm[c] * (double)Wc1[c * 16 + j];
      float zr = (float)z;
      zr = zr > 0.f ? zr : 0.f;
      o += (double)zr * (double)Wc2[j];
    }
    outp[g] = (float)o;
  }
}

// ---------------- launch ------------------------------------------------------------
extern "C" void kernel_launch(void* const* d_in, const int* in_sizes, int n_in,
                              void* d_out, int out_size, void* d_ws, size_t ws_size,
                              hipStream_t stream)
{
  const float* x      = (const float*)d_in[0];
  const int*   ei     = (const int*)d_in[1];
  const int*   batch  = (const int*)d_in[3];
  const float* W1     = (const float*)d_in[4];
  const float* a_src1 = (const float*)d_in[5];
  const float* a_dst1 = (const float*)d_in[6];
  const float* b1     = (const float*)d_in[7];
  const float* W2     = (const float*)d_in[8];
  const float* a_src2 = (const float*)d_in[9];
  const float* a_dst2 = (const float*)d_in[10];
  const float* b2     = (const float*)d_in[11];
  const float* Wc1    = (const float*)d_in[12];
  const float* bc1    = (const float*)d_in[13];
  const float* Wc2    = (const float*)d_in[14];
  const float* bc2    = (const float*)d_in[15];

  const int N = in_sizes[0] / 128;
  const int E = in_sizes[1] / 2;
  const int G = out_size;

  const int* srcv = ei;
  const int* dstv = ei + E;

  char* ws = (char*)d_ws;
  size_t off = 0;
  auto alloc = [&](size_t bytes) -> void* {
    void* p = ws + off;
    off += (bytes + 255) & ~(size_t)255;
    return p;
  };
  const int K  = (N + BUCKET_NODES - 1) >> BUCKET_SHIFT;    // buckets (<= MAX_BUCK)
  const int pb = (E + PART_CHUNK - 1) / PART_CHUNK;         // hist/partition blocks
  const int pbPad = (pb + 63) & ~63;

  _Float16* h1   = (_Float16*)alloc((size_t)N * 128 * 2);   // [N][128]
  _Float16* act1 = (_Float16*)alloc((size_t)N * 128 * 2);   // [N][128]
  _Float16* h2   = (_Float16*)alloc((size_t)N * 32 * 2);    // [N][32]
  float* act2  = (float*)alloc((size_t)N * 32 * 4);         // [N][32]
  float* as1   = (float*)alloc((size_t)N * 4 * 4);          // [N][4]
  float* ad1   = (float*)alloc((size_t)N * 4 * 4);
  float* as2   = (float*)alloc((size_t)N * 4);
  float* ad2   = (float*)alloc((size_t)N * 4);
  int*   rowStart = (int*)alloc((size_t)(N + 1) * 4);
  int*   colv     = (int*)alloc((size_t)E * 4);
  unsigned int* bucketed = (unsigned int*)alloc((size_t)E * 4);
  int*   bucketPartial = (int*)alloc((size_t)MAX_BUCK * pbPad * 4);  // [b][j]
  int*   bucketStart   = (int*)alloc((size_t)MAX_BUCK * 4);
  // ---- zeroed-aux region (contiguous; zeroed by launch-1 hist block 0) ----
  size_t zoff0 = off;
  float* pooled = (float*)alloc((size_t)G * 32 * 4);
  float* cntG   = (float*)alloc((size_t)G * 4);
  size_t zoff1 = off;
  const int zwords = (int)((zoff1 - zoff0) / 4);
  int* zbase = (int*)pooled;

  // 1) fused gemm1 + bucket-hist (+ aux zeroing)
  const int gemmBlocks = (N + 15) / 16;
  gemm1_hist_kernel<<<pb + gemmBlocks, 256, 0, stream>>>(
      x, W1, a_src1, a_dst1, h1, as1, ad1, N,
      dstv, bucketPartial, pbPad, E, K, pb, zbase, zwords);
  // 2) per-bucket parallel scan of chunk counts (totals -> bucketStart)
  scan_rows_kernel<<<K, 256, 0, stream>>>(bucketPartial, pbPad, bucketStart, pb);
  // 3) exclusive scan over bucket totals
  scan_buckets_kernel<<<1, 256, 0, stream>>>(bucketStart, K);
  // 4) partition (pure scatter)
  partition_kernel<<<pb, 256, 0, stream>>>(srcv, dstv, bucketStart, bucketPartial, pbPad,
                                           bucketed, E, K);
  // 5) per-bucket fill -> rowStart + col
  fill_csr_kernel<<<K, 256, 0, stream>>>(bucketed, bucketStart, rowStart, colv, N, E, K);
  // 6) layer-1 aggregation
  gat_aggr1_kernel<<<(N + 15) / 16, 256, 0, stream>>>(h1, as1, ad1, rowStart, colv, b1, act1, N);
  // 7) gemm2
  gemm2_kernel<<<(N + 7) / 8, 128, 0, stream>>>(act1, W2, a_src2, a_dst2, h2, as2, ad2, N);
  // 8) layer-2 aggregation
  gat_aggr2_kernel<<<(N + 31) / 32, 256, 0, stream>>>(h2, as2, ad2, rowStart, colv, b2, act2, N);
  // 9) pool
  pool_kernel<<<(N + 63) / 64, 256, 0, stream>>>(act2, batch, pooled, cntG, N);
  // 10) classifier
  classifier_kernel<<<(G + 255) / 256, 256, 0, stream>>>(pooled, cntG, Wc1, bc1, Wc2, bc2,
                                                         (float*)d_out, G);
}